// Round 10
// baseline (112.932 us; speedup 1.0000x reference)
//
#include <hip/hip_runtime.h>
#include <math.h>

// NT-Xent (SimCLR) loss. B=4096, D=256, T=0.5.
// R10: m201-style fine-phase 256^2. R9 failed from (a) 3-round tail
// (528 blocks @ 1 blk/CU) and (b) coarse stage-all/compute-all K-steps
// (m233: stage+vmcnt+barrier = ~72% stall at this structure). Fix:
//  - 4 phases/K-step: {ds_read subtile -> barrier -> 16 MFMA (setprio)
//    -> barrier}; bf regs held across h-phases; vmcnt(8) only at step
//    entry; stage(u+2) after trailing barrier (WAR-safe, 2 buffers).
//  - persistent 3 tiles/block, grid 176 (176*3=528): no 3rd-round tail;
//    flattened cross-tile step stream -> next tile's glds fly DURING the
//    epilogue (prologue paid once).
//  - epilogue uses raw s_barrier + lgkmcnt(0) (no __syncthreads -> no
//    vmcnt(0) drain of in-flight staging).
// Skeleton (layout/staging/epilogue/denomP slots) verified in R9.
//   zbF layout: rg = row>>4, s = k>>5:
//     offset_shorts = rg*4096 + s*512 + ((k>>3)&3)*128 + (row&15)*8 + (k&7)
// Rows scaled by sqrt(2/ln2): acc = 2*sim/ln2 -> epilogue exp2(acc);
// posv holds 2*sim/ln2; reduce weight = 2*ln2.

#define NROWS 8192
#define NHALF 4096
#define DIM   256
#define BMT   256
#define NCB   (NROWS / 128)           // denomP slot granularity (64 slots)
#define NCBT  (NROWS / BMT)           // 32 tile rows/cols
#define NTRIT (NCBT * (NCBT + 1) / 2) // 528 triangle tiles
#define GRID_D 176                    // 176 blocks x 3 tiles = 528

typedef __attribute__((ext_vector_type(8))) short bf16x8;
typedef __attribute__((ext_vector_type(4))) float f32x4;

static __device__ __forceinline__ unsigned short f2bf(float x) {
  unsigned int u = __float_as_uint(x);
  unsigned int r = (u + 0x7FFFu + ((u >> 16) & 1u)) >> 16;
  return (unsigned short)r;
}

// ---------------- normalize -> fragment-native layout (also zeroes out[0])
__global__ __launch_bounds__(256) void normalize_kernel(
    const float* __restrict__ emb_i, const float* __restrict__ emb_j,
    unsigned short* __restrict__ zbF, float* __restrict__ out) {
  __shared__ unsigned short tile[16 * DIM];  // 8 KB
  if (blockIdx.x == 0 && threadIdx.x == 0) out[0] = 0.f;
  const int w = threadIdx.x >> 6, lane = threadIdx.x & 63;
  const int rg = blockIdx.x;
  #pragma unroll
  for (int rr = 0; rr < 4; ++rr) {
    const int m16 = w * 4 + rr;
    const int row = rg * 16 + m16;
    const float* src = (row < NHALF) ? (emb_i + (size_t)row * DIM)
                                     : (emb_j + (size_t)(row - NHALF) * DIM);
    float4 v = ((const float4*)src)[lane];
    float ss = v.x * v.x + v.y * v.y + v.z * v.z + v.w * v.w;
    #pragma unroll
    for (int off = 32; off; off >>= 1) ss += __shfl_down(ss, off, 64);
    float total = __shfl(ss, 0, 64);
    // sqrt(2/ln2): acc = 2*sim/ln2, so epilogue is exp2(acc) directly.
    float inv = 1.69870077f / fmaxf(sqrtf(total), 1e-12f);
    ushort4 o;
    o.x = f2bf(v.x * inv); o.y = f2bf(v.y * inv);
    o.z = f2bf(v.z * inv); o.w = f2bf(v.w * inv);
    // k = lane*4 -> s = lane>>3, quad = (lane>>1)&3, j = (lane&1)*4
    const int s = lane >> 3, quad = (lane >> 1) & 3, jj = (lane & 1) * 4;
    *(ushort4*)&tile[s * 512 + (quad * 16 + m16) * 8 + jj] = o;
  }
  __syncthreads();
  uint4* dst = (uint4*)(zbF + (size_t)rg * (16 * DIM));
  const uint4* srcT = (const uint4*)tile;
  dst[threadIdx.x] = srcT[threadIdx.x];
  dst[256 + threadIdx.x] = srcT[256 + threadIdx.x];
}

// ------------------------------------------------ MFMA GEMM + exp + sums
__global__ __launch_bounds__(512, 2) void denom_kernel(
    const unsigned short* __restrict__ zbF, float* __restrict__ denomP,
    float* __restrict__ posv) {
  __shared__ unsigned short As[2][32 * 512];  // 2 x 32 KB
  __shared__ unsigned short Bs[2][32 * 512];  // 2 x 32 KB
  __shared__ float rowpart[4][256];           // 4 KB
  __shared__ float colpart[2][256];           // 2 KB

  const int tid = threadIdx.x;
  const int w = tid >> 6;             // 8 waves
  const int lane = tid & 63;
  const int wr = w >> 2, wc = w & 3;  // 2x4 wave grid; wave = 128x64 out
  const int quad = lane >> 4;
  const int m16 = lane & 15;

  auto decode = [](int t, int& bx, int& by) {
    by = (int)((sqrtf(8.0f * (float)t + 1.0f) - 1.0f) * 0.5f);
    while ((by + 1) * (by + 2) / 2 <= t) ++by;
    while (by * (by + 1) / 2 > t) --by;
    bx = t - by * (by + 1) / 2;
  };
  int bx0, by0, bx1, by1, bx2, by2;
  decode(blockIdx.x * 3 + 0, bx0, by0);
  decode(blockIdx.x * 3 + 1, bx1, by1);
  decode(blockIdx.x * 3 + 2, bx2, by2);
  const unsigned short* gA0 = zbF + (size_t)(bx0 * 16) * 4096 + lane * 8;
  const unsigned short* gB0 = zbF + (size_t)(by0 * 16) * 4096 + lane * 8;
  const unsigned short* gA1 = zbF + (size_t)(bx1 * 16) * 4096 + lane * 8;
  const unsigned short* gB1 = zbF + (size_t)(by1 * 16) * 4096 + lane * 8;
  const unsigned short* gA2 = zbF + (size_t)(bx2 * 16) * 4096 + lane * 8;
  const unsigned short* gB2 = zbF + (size_t)(by2 * 16) * 4096 + lane * 8;

  f32x4 acc[8][4];
  #pragma unroll
  for (int i = 0; i < 8; ++i)
    #pragma unroll
    for (int j = 0; j < 4; ++j) {
      f32x4 z4 = {0.f, 0.f, 0.f, 0.f};
      acc[i][j] = z4;
    }

  // stage K-step kt of a tile into buffer b: 32 A + 32 B 1 KB chunks; wave w
  // takes chunks w*4..w*4+3 of each (8 glds/wave, FIFO A,B,A,B..).
  auto stage = [&](int b, const unsigned short* gA_,
                   const unsigned short* gB_, int kt) {
    #pragma unroll
    for (int cc = 0; cc < 4; ++cc) {
      const int c = w * 4 + cc;
      const size_t goff = (size_t)(c >> 1) * 4096 + (kt * 2 + (c & 1)) * 512;
      __builtin_amdgcn_global_load_lds(
          (const __attribute__((address_space(1))) unsigned int*)(gA_ + goff),
          (__attribute__((address_space(3))) unsigned int*)&As[b][c * 512],
          16, 0, 0);
      __builtin_amdgcn_global_load_lds(
          (const __attribute__((address_space(1))) unsigned int*)(gB_ + goff),
          (__attribute__((address_space(3))) unsigned int*)&Bs[b][c * 512],
          16, 0, 0);
    }
  };

  bf16x8 af[4], bf[4];

#define BARm()                                   \
  __builtin_amdgcn_s_barrier();                  \
  asm volatile("" ::: "memory")

#define PH_LOADB(BUF, S32)                                                \
  do {                                                                    \
    _Pragma("unroll") for (int j = 0; j < 4; ++j)                         \
        bf[j] = *(const bf16x8*)                                          \
            &Bs[BUF][((wc * 4 + j) * 2 + (S32)) * 512 + lane * 8];        \
  } while (0)

#define PH_LOADA(BUF, S32, H)                                             \
  do {                                                                    \
    _Pragma("unroll") for (int i4 = 0; i4 < 4; ++i4)                      \
        af[i4] = *(const bf16x8*)                                         \
            &As[BUF][((wr * 8 + (H)*4 + i4) * 2 + (S32)) * 512 +          \
                     lane * 8];                                           \
  } while (0)

#define PH_MFMA(H)                                                        \
  do {                                                                    \
    __builtin_amdgcn_s_setprio(1);                                        \
    _Pragma("unroll") for (int i4 = 0; i4 < 4; ++i4)                      \
        _Pragma("unroll") for (int j = 0; j < 4; ++j)                     \
            acc[(H)*4 + i4][j] = __builtin_amdgcn_mfma_f32_16x16x32_bf16( \
                af[i4], bf[j], acc[(H)*4 + i4][j], 0, 0, 0);              \
    __builtin_amdgcn_s_setprio(0);                                        \
  } while (0)

  // One K-step (K=64) on buffer BUF, 4 fine phases; then stage step u+2.
  // Every wave waits its own vmcnt before the entry barrier -> after the
  // barrier ALL waves' step-u glds have landed.
#define KSTEP(BUF, WN, DOSTG, GAS, GBS, KTS)                              \
  do {                                                                    \
    asm volatile("s_waitcnt vmcnt(" #WN ")" ::: "memory");                \
    BARm();                                                               \
    PH_LOADB(BUF, 0); PH_LOADA(BUF, 0, 0); PH_MFMA(0);                    \
    BARm();                                                               \
    PH_LOADA(BUF, 0, 1); PH_MFMA(1);                                      \
    BARm();                                                               \
    PH_LOADB(BUF, 1); PH_LOADA(BUF, 1, 0); PH_MFMA(0);                    \
    BARm();                                                               \
    PH_LOADA(BUF, 1, 1); PH_MFMA(1);                                      \
    BARm();                                                               \
    if (DOSTG) stage(BUF, GAS, GBS, KTS);                                 \
  } while (0)

  // Per-tile epilogue (exp2 + reductions + denomP/posv) then acc reset.
  // Raw barriers + lgkmcnt(0) only -- keeps next tile's glds in flight.
  auto epilogue = [&](int bx, int by) {
    const int row0 = bx * BMT, col0 = by * BMT;
    if (col0 - row0 == NHALF) {
      #pragma unroll
      for (int i = 0; i < 8; ++i)
        #pragma unroll
        for (int j = 0; j < 4; ++j) {
          int gcol = col0 + wc * 64 + j * 16 + m16;
          #pragma unroll
          for (int r = 0; r < 4; ++r) {
            int grow = row0 + wr * 128 + i * 16 + quad * 4 + r;
            if (gcol - grow == NHALF) posv[grow] = acc[i][j][r];
          }
        }
    }
    float rs[8][4];
    float cs[4] = {0.f, 0.f, 0.f, 0.f};
    #pragma unroll
    for (int i = 0; i < 8; ++i)
      #pragma unroll
      for (int r = 0; r < 4; ++r) rs[i][r] = 0.f;
    if (bx != by) {
      #pragma unroll
      for (int i = 0; i < 8; ++i)
        #pragma unroll
        for (int j = 0; j < 4; ++j)
          #pragma unroll
          for (int r = 0; r < 4; ++r) {
            float e = __builtin_amdgcn_exp2f(acc[i][j][r]);
            rs[i][r] += e;
            cs[j] += e;
          }
    } else {
      #pragma unroll
      for (int i = 0; i < 8; ++i)
        #pragma unroll
        for (int j = 0; j < 4; ++j) {
          int gcol = col0 + wc * 64 + j * 16 + m16;
          #pragma unroll
          for (int r = 0; r < 4; ++r) {
            int grow = row0 + wr * 128 + i * 16 + quad * 4 + r;
            float e =
                (grow == gcol) ? 0.f : __builtin_amdgcn_exp2f(acc[i][j][r]);
            rs[i][r] += e;
            cs[j] += e;
          }
        }
    }
    #pragma unroll
    for (int i = 0; i < 8; ++i)
      #pragma unroll
      for (int r = 0; r < 4; ++r) {
        float v = rs[i][r];
        v += __shfl_xor(v, 1, 16);
        v += __shfl_xor(v, 2, 16);
        v += __shfl_xor(v, 4, 16);
        v += __shfl_xor(v, 8, 16);
        if (m16 == 0) rowpart[wc][wr * 128 + i * 16 + quad * 4 + r] = v;
      }
    #pragma unroll
    for (int j = 0; j < 4; ++j) {
      float v = cs[j];
      v += __shfl_xor(v, 16, 64);
      v += __shfl_xor(v, 32, 64);
      if (quad == 0) colpart[wr][wc * 64 + j * 16 + m16] = v;
    }
    asm volatile("s_waitcnt lgkmcnt(0)" ::: "memory");
    BARm();
    if (tid < 256) {
      denomP[(size_t)(2 * by) * NROWS + row0 + tid] = rowpart[0][tid] +
          rowpart[1][tid] + rowpart[2][tid] + rowpart[3][tid];
    } else if (bx != by) {
      int c = tid - 256;
      denomP[(size_t)(2 * bx) * NROWS + col0 + c] =
          colpart[0][c] + colpart[1][c];
    }
    #pragma unroll
    for (int i = 0; i < 8; ++i)
      #pragma unroll
      for (int j = 0; j < 4; ++j) {
        f32x4 z4 = {0.f, 0.f, 0.f, 0.f};
        acc[i][j] = z4;
      }
  };

  // ---- flattened 12-step stream over 3 tiles (2-buffer, 2-deep) ----
  stage(0, gA0, gB0, 0);
  stage(1, gA0, gB0, 1);
  KSTEP(0, 8, 1, gA0, gB0, 2);   // u0
  KSTEP(1, 8, 1, gA0, gB0, 3);   // u1
  KSTEP(0, 8, 1, gA1, gB1, 0);   // u2
  KSTEP(1, 8, 1, gA1, gB1, 1);   // u3
  epilogue(bx0, by0);            // t1's k0/k1 glds fly under this
  KSTEP(0, 8, 1, gA1, gB1, 2);   // u4
  KSTEP(1, 8, 1, gA1, gB1, 3);   // u5
  KSTEP(0, 8, 1, gA2, gB2, 0);   // u6
  KSTEP(1, 8, 1, gA2, gB2, 1);   // u7
  epilogue(bx1, by1);
  KSTEP(0, 8, 1, gA2, gB2, 2);   // u8
  KSTEP(1, 8, 1, gA2, gB2, 3);   // u9
  KSTEP(0, 8, 0, gA2, gB2, 0);   // u10 (no stage)
  KSTEP(1, 0, 0, gA2, gB2, 0);   // u11 (drain)
  epilogue(bx2, by2);
#undef KSTEP
#undef PH_MFMA
#undef PH_LOADA
#undef PH_LOADB
#undef BARm
}

// -------------------- denom slots -> -log; + 2*ln2*pos'; atomic into loss
__global__ __launch_bounds__(256) void reduce_kernel(
    const float* __restrict__ denomP, const float* __restrict__ posv,
    float* __restrict__ out) {
  int tid = threadIdx.x;
  int r = blockIdx.x * 256 + tid;  // 32 blocks cover 8192 rows
  float s = 0.f;
  // 256-tiles write only even slots (2*by for by in 0..31) -> stride 2.
  #pragma unroll 8
  for (int b = 0; b < NCB; b += 2) s += denomP[(size_t)b * NROWS + r];
  float v = -logf(s);
  // posv = 2*sim/ln2; need 4*sim (rows r and r+NHALF) = 2*ln2*posv
  if (r < NHALF) v += 1.38629436112f * posv[r];
  #pragma unroll
  for (int off = 32; off; off >>= 1) v += __shfl_down(v, off, 64);
  __shared__ float s4[4];
  if ((tid & 63) == 0) s4[tid >> 6] = v;
  __syncthreads();
  if (tid == 0)
    atomicAdd(out, (s4[0] + s4[1] + s4[2] + s4[3]) * (1.0f / 8192.0f));
}

extern "C" void kernel_launch(void* const* d_in, const int* in_sizes, int n_in,
                              void* d_out, int out_size, void* d_ws,
                              size_t ws_size, hipStream_t stream) {
  const float* emb_i = (const float*)d_in[0];
  const float* emb_j = (const float*)d_in[1];
  unsigned short* zbF = (unsigned short*)d_ws;           // 4 MB (frag layout)
  float* denomP = (float*)(zbF + (size_t)NROWS * DIM);   // 64*8192 f32 (2 MB)
  float* posv = denomP + (size_t)NCB * NROWS;            // 4096 f32
  float* out = (float*)d_out;

  normalize_kernel<<<NROWS / 16, 256, 0, stream>>>(emb_i, emb_j, zbF, out);
  denom_kernel<<<GRID_D, 512, 0, stream>>>(zbF, denomP, posv);
  reduce_kernel<<<NROWS / 256, 256, 0, stream>>>(denomP, posv, out);
}

// Round 11
// 112.724 us; speedup vs baseline: 1.0018x; 1.0018x over previous
//
#include <hip/hip_runtime.h>
#include <math.h>

// NT-Xent (SimCLR) loss. B=4096, D=256, T=0.5.
// R11: 256^2 tile at 2 blocks/CU (the config R9/R10 never actually tested:
// R9 = 1 blk/CU + 3-round tail; R10 = 176-CU grid + 1 blk/CU). BK=32 halves
// LDS to 70 KB -> 2 blk/CU, 16 waves/CU. Grid = 528 (2 full rounds + 16-blk
// tail). R6-proven phase pattern: counted vmcnt(4) -> barrier -> compute
// (32 MFMA) -> barrier -> stage(ks+2); 8 K-steps, 4 glds/wave/step, 2-deep.
// Per-CU pipe sums at 256^2: VMEM 3.4us, LDS-read ~8us, MFMA 7us (vs 128^2's
// VMEM 10.4) -- max-pipe ~8us, so even at the empirical 2-3x slack this
// structure should land well under the 42us wall of all 128^2 schedules.
// Epilogue/decode/denomP slots verbatim from R9 (verified correct).
//   zbF layout: rg = row>>4, s = k>>5:
//     offset_shorts = rg*4096 + s*512 + ((k>>3)&3)*128 + (row&15)*8 + (k&7)
// Rows scaled by sqrt(2/ln2): acc = 2*sim/ln2 -> epilogue exp2(acc);
// posv holds 2*sim/ln2; reduce weight = 2*ln2; stride-2 denomP slots.

#define NROWS 8192
#define NHALF 4096
#define DIM   256
#define BMT   256
#define NCB   (NROWS / 128)           // denomP slot granularity (64 slots)
#define NCBT  (NROWS / BMT)           // 32 tile rows/cols
#define NTRIT (NCBT * (NCBT + 1) / 2) // 528 triangle tiles

typedef __attribute__((ext_vector_type(8))) short bf16x8;
typedef __attribute__((ext_vector_type(4))) float f32x4;

static __device__ __forceinline__ unsigned short f2bf(float x) {
  unsigned int u = __float_as_uint(x);
  unsigned int r = (u + 0x7FFFu + ((u >> 16) & 1u)) >> 16;
  return (unsigned short)r;
}

// ---------------- normalize -> fragment-native layout (also zeroes out[0])
__global__ __launch_bounds__(256) void normalize_kernel(
    const float* __restrict__ emb_i, const float* __restrict__ emb_j,
    unsigned short* __restrict__ zbF, float* __restrict__ out) {
  __shared__ unsigned short tile[16 * DIM];  // 8 KB
  if (blockIdx.x == 0 && threadIdx.x == 0) out[0] = 0.f;
  const int w = threadIdx.x >> 6, lane = threadIdx.x & 63;
  const int rg = blockIdx.x;
  #pragma unroll
  for (int rr = 0; rr < 4; ++rr) {
    const int m16 = w * 4 + rr;
    const int row = rg * 16 + m16;
    const float* src = (row < NHALF) ? (emb_i + (size_t)row * DIM)
                                     : (emb_j + (size_t)(row - NHALF) * DIM);
    float4 v = ((const float4*)src)[lane];
    float ss = v.x * v.x + v.y * v.y + v.z * v.z + v.w * v.w;
    #pragma unroll
    for (int off = 32; off; off >>= 1) ss += __shfl_down(ss, off, 64);
    float total = __shfl(ss, 0, 64);
    // sqrt(2/ln2): acc = 2*sim/ln2, so epilogue is exp2(acc) directly.
    float inv = 1.69870077f / fmaxf(sqrtf(total), 1e-12f);
    ushort4 o;
    o.x = f2bf(v.x * inv); o.y = f2bf(v.y * inv);
    o.z = f2bf(v.z * inv); o.w = f2bf(v.w * inv);
    // k = lane*4 -> s = lane>>3, quad = (lane>>1)&3, j = (lane&1)*4
    const int s = lane >> 3, quad = (lane >> 1) & 3, jj = (lane & 1) * 4;
    *(ushort4*)&tile[s * 512 + (quad * 16 + m16) * 8 + jj] = o;
  }
  __syncthreads();
  uint4* dst = (uint4*)(zbF + (size_t)rg * (16 * DIM));
  const uint4* srcT = (const uint4*)tile;
  dst[threadIdx.x] = srcT[threadIdx.x];
  dst[256 + threadIdx.x] = srcT[256 + threadIdx.x];
}

// ------------------------------------------------ MFMA GEMM + exp + sums
__global__ __launch_bounds__(512, 2) void denom_kernel(
    const unsigned short* __restrict__ zbF, float* __restrict__ denomP,
    float* __restrict__ posv) {
  __shared__ unsigned short As[2][16 * 512];  // 2 x 16 KB (K=32 slice)
  __shared__ unsigned short Bs[2][16 * 512];  // 2 x 16 KB
  __shared__ float rowpart[4][256];           // 4 KB
  __shared__ float colpart[2][256];           // 2 KB  -> total 70 KB

  // XCD-aware bijective swizzle (528 % 8 == 0)
  int t = (blockIdx.x & 7) * (NTRIT / 8) + (blockIdx.x >> 3);
  int by = (int)((sqrtf(8.0f * (float)t + 1.0f) - 1.0f) * 0.5f);
  while ((by + 1) * (by + 2) / 2 <= t) ++by;
  while (by * (by + 1) / 2 > t) --by;
  int bx = t - by * (by + 1) / 2;

  const int tid = threadIdx.x;
  const int w = tid >> 6;             // 8 waves
  const int lane = tid & 63;
  const int wr = w >> 2, wc = w & 3;  // 2x4 wave grid; wave = 128x64 out
  const int quad = lane >> 4;
  const int m16 = lane & 15;
  const int row0 = bx * BMT;
  const int col0 = by * BMT;

  // frag-native panels: 16 rgs per 256-row panel, 8 K32-slices each.
  const unsigned short* gA = zbF + (size_t)(bx * 16) * 4096 + lane * 8;
  const unsigned short* gB = zbF + (size_t)(by * 16) * 4096 + lane * 8;

  f32x4 acc[8][4];
  #pragma unroll
  for (int i = 0; i < 8; ++i)
    #pragma unroll
    for (int j = 0; j < 4; ++j) {
      f32x4 z4 = {0.f, 0.f, 0.f, 0.f};
      acc[i][j] = z4;
    }

  // stage K32-slice kt into buffer b: 16 A + 16 B 1 KB chunks; wave w takes
  // rgs {2w, 2w+1} of each (4 glds/wave, FIFO). Linear LDS dest = frag layout.
  auto stage = [&](int b, int kt) {
    #pragma unroll
    for (int cc = 0; cc < 2; ++cc) {
      const int rg = w * 2 + cc;
      const size_t goff = (size_t)rg * 4096 + kt * 512;
      __builtin_amdgcn_global_load_lds(
          (const __attribute__((address_space(1))) unsigned int*)(gA + goff),
          (__attribute__((address_space(3))) unsigned int*)&As[b][rg * 512],
          16, 0, 0);
      __builtin_amdgcn_global_load_lds(
          (const __attribute__((address_space(1))) unsigned int*)(gB + goff),
          (__attribute__((address_space(3))) unsigned int*)&Bs[b][rg * 512],
          16, 0, 0);
    }
  };

  // compute K32-slice from buffer b: 8 A-frags x 4 B-frags = 32 MFMA/wave.
  auto compute = [&](int b) {
    bf16x8 bf[4];
    #pragma unroll
    for (int j = 0; j < 4; ++j)
      bf[j] = *(const bf16x8*)&Bs[b][(wc * 4 + j) * 512 + lane * 8];
    #pragma unroll
    for (int i = 0; i < 8; ++i) {
      bf16x8 af = *(const bf16x8*)&As[b][(wr * 8 + i) * 512 + lane * 8];
      __builtin_amdgcn_s_setprio(1);
      #pragma unroll
      for (int j = 0; j < 4; ++j)
        acc[i][j] = __builtin_amdgcn_mfma_f32_16x16x32_bf16(
            af, bf[j], acc[i][j], 0, 0, 0);
      __builtin_amdgcn_s_setprio(0);
    }
  };

  // ---- counted-vmcnt 2-buffer pipeline, 8 K32-steps (R6-proven pattern).
  // 4 glds/stage/wave: in-flight at step entry = 8 -> vmcnt(4) retires the
  // oldest stage; barrier; compute; barrier (WAR); stage(ks+2).
  stage(0, 0);
  stage(1, 1);
#define KSTEP(BUF, WN, DOSTG, KTS)                                  \
  do {                                                              \
    asm volatile("s_waitcnt vmcnt(" #WN ")" ::: "memory");          \
    __builtin_amdgcn_s_barrier();                                   \
    asm volatile("" ::: "memory");                                  \
    compute(BUF);                                                   \
    asm volatile("" ::: "memory");                                  \
    __builtin_amdgcn_s_barrier();                                   \
    asm volatile("" ::: "memory");                                  \
    if (DOSTG) stage(BUF, KTS);                                     \
  } while (0)
  KSTEP(0, 4, 1, 2);
  KSTEP(1, 4, 1, 3);
  KSTEP(0, 4, 1, 4);
  KSTEP(1, 4, 1, 5);
  KSTEP(0, 4, 1, 6);
  KSTEP(1, 4, 1, 7);
  KSTEP(0, 4, 0, 0);
  KSTEP(1, 0, 0, 0);
#undef KSTEP

  // pos extraction: tiles with col0 == row0 + NHALF (by == bx+16).
  if (col0 - row0 == NHALF) {
    #pragma unroll
    for (int i = 0; i < 8; ++i)
      #pragma unroll
      for (int j = 0; j < 4; ++j) {
        int gcol = col0 + wc * 64 + j * 16 + m16;
        #pragma unroll
        for (int r = 0; r < 4; ++r) {
          int grow = row0 + wr * 128 + i * 16 + quad * 4 + r;
          if (gcol - grow == NHALF) posv[grow] = acc[i][j][r];
        }
      }
  }

  // Epilogue: e = exp2(acc) = exp(2*sim). Diagonal tiles (bx==by, 32 of
  // 528) pay the grow==gcol compare; off-diagonal tiles skip it.
  float rs[8][4];
  float cs[4] = {0.f, 0.f, 0.f, 0.f};
  #pragma unroll
  for (int i = 0; i < 8; ++i)
    #pragma unroll
    for (int r = 0; r < 4; ++r) rs[i][r] = 0.f;

  if (bx != by) {
    #pragma unroll
    for (int i = 0; i < 8; ++i)
      #pragma unroll
      for (int j = 0; j < 4; ++j)
        #pragma unroll
        for (int r = 0; r < 4; ++r) {
          float e = __builtin_amdgcn_exp2f(acc[i][j][r]);
          rs[i][r] += e;
          cs[j] += e;
        }
  } else {
    #pragma unroll
    for (int i = 0; i < 8; ++i)
      #pragma unroll
      for (int j = 0; j < 4; ++j) {
        int gcol = col0 + wc * 64 + j * 16 + m16;
        #pragma unroll
        for (int r = 0; r < 4; ++r) {
          int grow = row0 + wr * 128 + i * 16 + quad * 4 + r;
          float e =
              (grow == gcol) ? 0.f : __builtin_amdgcn_exp2f(acc[i][j][r]);
          rs[i][r] += e;
          cs[j] += e;
        }
      }
  }

  // rowsum: reduce across the 16 column lanes (same quad); 4 wc partials.
  #pragma unroll
  for (int i = 0; i < 8; ++i)
    #pragma unroll
    for (int r = 0; r < 4; ++r) {
      float v = rs[i][r];
      v += __shfl_xor(v, 1, 16);
      v += __shfl_xor(v, 2, 16);
      v += __shfl_xor(v, 4, 16);
      v += __shfl_xor(v, 8, 16);
      if (m16 == 0) rowpart[wc][wr * 128 + i * 16 + quad * 4 + r] = v;
    }
  // colsum: reduce across the 4 quads; 2 wr partials.
  #pragma unroll
  for (int j = 0; j < 4; ++j) {
    float v = cs[j];
    v += __shfl_xor(v, 16, 64);
    v += __shfl_xor(v, 32, 64);
    if (quad == 0) colpart[wr][wc * 64 + j * 16 + m16] = v;
  }
  __syncthreads();

  // denomP slots are 128-row granular (NCB=64): 256-tile (bx,by) writes
  // rowsums at slot 2*by (rows [row0,row0+256)) and colsums at slot 2*bx.
  if (tid < 256) {
    denomP[(size_t)(2 * by) * NROWS + row0 + tid] =
        rowpart[0][tid] + rowpart[1][tid] + rowpart[2][tid] + rowpart[3][tid];
  } else if (bx != by) {
    int c = tid - 256;
    denomP[(size_t)(2 * bx) * NROWS + col0 + c] =
        colpart[0][c] + colpart[1][c];
  }
}

// -------------------- denom slots -> -log; + 2*ln2*pos'; atomic into loss
__global__ __launch_bounds__(256) void reduce_kernel(
    const float* __restrict__ denomP, const float* __restrict__ posv,
    float* __restrict__ out) {
  int tid = threadIdx.x;
  int r = blockIdx.x * 256 + tid;  // 32 blocks cover 8192 rows
  float s = 0.f;
  // 256-tiles write only even slots (2*by for by in 0..31) -> stride 2.
  #pragma unroll 8
  for (int b = 0; b < NCB; b += 2) s += denomP[(size_t)b * NROWS + r];
  float v = -logf(s);
  // posv = 2*sim/ln2; need 4*sim (rows r and r+NHALF) = 2*ln2*posv
  if (r < NHALF) v += 1.38629436112f * posv[r];
  #pragma unroll
  for (int off = 32; off; off >>= 1) v += __shfl_down(v, off, 64);
  __shared__ float s4[4];
  if ((tid & 63) == 0) s4[tid >> 6] = v;
  __syncthreads();
  if (tid == 0)
    atomicAdd(out, (s4[0] + s4[1] + s4[2] + s4[3]) * (1.0f / 8192.0f));
}

extern "C" void kernel_launch(void* const* d_in, const int* in_sizes, int n_in,
                              void* d_out, int out_size, void* d_ws,
                              size_t ws_size, hipStream_t stream) {
  const float* emb_i = (const float*)d_in[0];
  const float* emb_j = (const float*)d_in[1];
  unsigned short* zbF = (unsigned short*)d_ws;           // 4 MB (frag layout)
  float* denomP = (float*)(zbF + (size_t)NROWS * DIM);   // 64*8192 f32 (2 MB)
  float* posv = denomP + (size_t)NCB * NROWS;            // 4096 f32
  float* out = (float*)d_out;

  normalize_kernel<<<NROWS / 16, 256, 0, stream>>>(emb_i, emb_j, zbF, out);
  denom_kernel<<<NTRIT, 512, 0, stream>>>(zbF, denomP, posv);
  reduce_kernel<<<NROWS / 256, 256, 0, stream>>>(denomP, posv, out);
}

// Round 12
// 96.380 us; speedup vs baseline: 1.1717x; 1.1696x over previous
//
#include <hip/hip_runtime.h>
#include <math.h>

// NT-Xent (SimCLR) loss. B=4096, D=256, T=0.5.
// R12: R6's schedule + REGISTER DIET -> 4 blocks/CU. Session-wide pattern:
// six denom structures (barriers/traffic/tile all varied 2-4x) pinned at
// 40-55us, and ALL sat at <=12 waves/CU because every one carried >=160
// regs/wave (acc 64 AGPR + ~96 arch; gfx950 unified file, 512 slots/SIMD
// -> 3 waves/SIMD). The untested lever: occupancy. This kernel targets
// 128 total regs (64 AGPR + <=64 arch; per-i af temp keeps K-loop live set
// ~32) via __launch_bounds__(256,4) -> 4 waves/SIMD = 16 waves/CU.
// Schedule is R6 verbatim: 2-buffer glds staging, counted vmcnt(4), two
// raw barriers per K32-step, stage(ks+2) after the WAR barrier.
//   zbF layout: rg = row>>4, s = k>>5:
//     offset_shorts = rg*4096 + s*512 + ((k>>3)&3)*128 + (row&15)*8 + (k&7)
// Rows scaled by sqrt(2/ln2): acc = 2*sim/ln2 -> epilogue exp2(acc);
// posv holds 2*sim/ln2; reduce weight = 2*ln2.
// Spill tripwire: WRITE_SIZE >> 10 MB or denom >= 100us -> diet failed,
// 12-wave plateau is register-structural.

#define NROWS 8192
#define NHALF 4096
#define DIM   256
#define BM    128
#define BN    128
#define NCB   (NROWS / BN)          // 64 row/col blocks
#define NTRI  (NCB * (NCB + 1) / 2) // 2080 triangle tiles

typedef __attribute__((ext_vector_type(8))) short bf16x8;
typedef __attribute__((ext_vector_type(4))) float f32x4;

static __device__ __forceinline__ unsigned short f2bf(float x) {
  unsigned int u = __float_as_uint(x);
  unsigned int r = (u + 0x7FFFu + ((u >> 16) & 1u)) >> 16;
  return (unsigned short)r;
}

// ---------------- normalize -> fragment-native layout (also zeroes out[0])
__global__ __launch_bounds__(256) void normalize_kernel(
    const float* __restrict__ emb_i, const float* __restrict__ emb_j,
    unsigned short* __restrict__ zbF, float* __restrict__ out) {
  __shared__ unsigned short tile[16 * DIM];  // 8 KB
  if (blockIdx.x == 0 && threadIdx.x == 0) out[0] = 0.f;
  const int w = threadIdx.x >> 6, lane = threadIdx.x & 63;
  const int rg = blockIdx.x;
  #pragma unroll
  for (int rr = 0; rr < 4; ++rr) {
    const int m16 = w * 4 + rr;
    const int row = rg * 16 + m16;
    const float* src = (row < NHALF) ? (emb_i + (size_t)row * DIM)
                                     : (emb_j + (size_t)(row - NHALF) * DIM);
    float4 v = ((const float4*)src)[lane];
    float ss = v.x * v.x + v.y * v.y + v.z * v.z + v.w * v.w;
    #pragma unroll
    for (int off = 32; off; off >>= 1) ss += __shfl_down(ss, off, 64);
    float total = __shfl(ss, 0, 64);
    // sqrt(2/ln2): acc = 2*sim/ln2, so epilogue is exp2(acc) directly.
    float inv = 1.69870077f / fmaxf(sqrtf(total), 1e-12f);
    ushort4 o;
    o.x = f2bf(v.x * inv); o.y = f2bf(v.y * inv);
    o.z = f2bf(v.z * inv); o.w = f2bf(v.w * inv);
    // k = lane*4 -> s = lane>>3, quad = (lane>>1)&3, j = (lane&1)*4
    const int s = lane >> 3, quad = (lane >> 1) & 3, jj = (lane & 1) * 4;
    *(ushort4*)&tile[s * 512 + (quad * 16 + m16) * 8 + jj] = o;
  }
  __syncthreads();
  uint4* dst = (uint4*)(zbF + (size_t)rg * (16 * DIM));
  const uint4* srcT = (const uint4*)tile;
  dst[threadIdx.x] = srcT[threadIdx.x];
  dst[256 + threadIdx.x] = srcT[256 + threadIdx.x];
}

// ------------------------------------------------ MFMA GEMM + exp + sums
__global__ __launch_bounds__(256, 4) void denom_kernel(
    const unsigned short* __restrict__ zbF, float* __restrict__ denomP,
    float* __restrict__ posv) {
  __shared__ unsigned short As[2][8 * 512];  // 2 x 8 KB (one K=32 A-slice)
  __shared__ unsigned short Bs[2][8 * 512];  // 2 x 8 KB
  __shared__ float red[512];                 // 2 KB -> 34 KB total, 4 blk/CU

  // XCD-aware bijective swizzle (2080 % 8 == 0)
  int t = (blockIdx.x & 7) * (NTRI / 8) + (blockIdx.x >> 3);
  int by = (int)((sqrtf(8.0f * (float)t + 1.0f) - 1.0f) * 0.5f);
  while ((by + 1) * (by + 2) / 2 <= t) ++by;
  while (by * (by + 1) / 2 > t) --by;
  int bx = t - by * (by + 1) / 2;

  const int tid = threadIdx.x;
  const int w = tid >> 6;
  const int lane = tid & 63;
  const int wr = w >> 1, wc = w & 1;  // 2x2 wave grid, 64x64 each
  const int quad = lane >> 4;
  const int m16 = lane & 15;
  const int row0 = bx * BM;
  const int col0 = by * BN;

  // Staging pointers (per-lane 16 B within each 1 KB chunk).
  const unsigned short* gA = zbF + (size_t)(bx * 8) * 4096 + lane * 8;
  const unsigned short* gB = zbF + (size_t)(by * 8) * 4096 + lane * 8;

  f32x4 acc[4][4];
  #pragma unroll
  for (int i = 0; i < 4; ++i)
    #pragma unroll
    for (int j = 0; j < 4; ++j) {
      f32x4 z4 = {0.f, 0.f, 0.f, 0.f};
      acc[i][j] = z4;
    }

  // stage K=32 slice ks into buffer b: 8 A + 8 B 1 KB chunks; wave w takes
  // chunks {w, w+4} of each (4 glds/wave, FIFO A,B,A,B).
  auto stage = [&](int b, int ks) {
    #pragma unroll
    for (int r = 0; r < 2; ++r) {
      const int c = r * 4 + w;
      __builtin_amdgcn_global_load_lds(
          (const __attribute__((address_space(1))) unsigned int*)(gA +
              (size_t)c * 4096 + ks * 512),
          (__attribute__((address_space(3))) unsigned int*)&As[b][c * 512],
          16, 0, 0);
      __builtin_amdgcn_global_load_lds(
          (const __attribute__((address_space(1))) unsigned int*)(gB +
              (size_t)c * 4096 + ks * 512),
          (__attribute__((address_space(3))) unsigned int*)&Bs[b][c * 512],
          16, 0, 0);
    }
  };

  // compute: per-i af temp keeps the K-loop live set small (reg diet).
  auto compute = [&](int b) {
    bf16x8 bfr[4];
    #pragma unroll
    for (int j = 0; j < 4; ++j)
      bfr[j] = *(const bf16x8*)&Bs[b][(wc * 4 + j) * 512 + lane * 8];
    #pragma unroll
    for (int i = 0; i < 4; ++i) {
      bf16x8 af = *(const bf16x8*)&As[b][(wr * 4 + i) * 512 + lane * 8];
      __builtin_amdgcn_s_setprio(1);
      #pragma unroll
      for (int j = 0; j < 4; ++j)
        acc[i][j] = __builtin_amdgcn_mfma_f32_16x16x32_bf16(
            af, bfr[j], acc[i][j], 0, 0, 0);
      __builtin_amdgcn_s_setprio(0);
    }
  };

  // ---- counted-vmcnt 2-buffer pipeline (R6-proven), 8 K32-steps ----
  stage(0, 0);
  stage(1, 1);
#define PHASE(ks, NWAIT, DO_STAGE)                                  \
  do {                                                              \
    asm volatile("s_waitcnt vmcnt(" #NWAIT ")" ::: "memory");       \
    __builtin_amdgcn_s_barrier();                                   \
    asm volatile("" ::: "memory");                                  \
    compute((ks) & 1);                                              \
    asm volatile("" ::: "memory");                                  \
    __builtin_amdgcn_s_barrier();                                   \
    asm volatile("" ::: "memory");                                  \
    if (DO_STAGE) stage((ks) & 1, (ks) + 2);                        \
  } while (0)
  PHASE(0, 4, 1);
  PHASE(1, 4, 1);
  PHASE(2, 4, 1);
  PHASE(3, 4, 1);
  PHASE(4, 4, 1);
  PHASE(5, 4, 1);
  PHASE(6, 4, 0);
  PHASE(7, 0, 0);
#undef PHASE

  // pos extraction: only tiles with col0 == row0 + NHALF hold pair elements.
  if (col0 - row0 == NHALF) {
    #pragma unroll
    for (int i = 0; i < 4; ++i)
      #pragma unroll
      for (int j = 0; j < 4; ++j) {
        int gcol = col0 + wc * 64 + j * 16 + m16;
        #pragma unroll
        for (int r = 0; r < 4; ++r) {
          int grow = row0 + wr * 64 + i * 16 + quad * 4 + r;
          if (gcol - grow == NHALF) posv[grow] = acc[i][j][r];
        }
      }
  }

  // Epilogue: e = exp2(acc) = exp(2*sim). Diagonal tiles (bx==by, 64 of
  // 2080) pay the grow==gcol compare; off-diagonal tiles skip it.
  float rs[4][4];
  float cs[4] = {0.f, 0.f, 0.f, 0.f};
  #pragma unroll
  for (int i = 0; i < 4; ++i)
    #pragma unroll
    for (int r = 0; r < 4; ++r) rs[i][r] = 0.f;

  if (bx != by) {
    #pragma unroll
    for (int i = 0; i < 4; ++i)
      #pragma unroll
      for (int j = 0; j < 4; ++j)
        #pragma unroll
        for (int r = 0; r < 4; ++r) {
          float e = __builtin_amdgcn_exp2f(acc[i][j][r]);
          rs[i][r] += e;
          cs[j] += e;
        }
  } else {
    #pragma unroll
    for (int i = 0; i < 4; ++i)
      #pragma unroll
      for (int j = 0; j < 4; ++j) {
        int gcol = col0 + wc * 64 + j * 16 + m16;
        #pragma unroll
        for (int r = 0; r < 4; ++r) {
          int grow = row0 + wr * 64 + i * 16 + quad * 4 + r;
          float e =
              (grow == gcol) ? 0.f : __builtin_amdgcn_exp2f(acc[i][j][r]);
          rs[i][r] += e;
          cs[j] += e;
        }
      }
  }

  // rowsum: reduce across the 16 column lanes (same quad)
  #pragma unroll
  for (int i = 0; i < 4; ++i)
    #pragma unroll
    for (int r = 0; r < 4; ++r) {
      float v = rs[i][r];
      v += __shfl_xor(v, 1, 16);
      v += __shfl_xor(v, 2, 16);
      v += __shfl_xor(v, 4, 16);
      v += __shfl_xor(v, 8, 16);
      if (m16 == 0) red[wc * 128 + wr * 64 + i * 16 + quad * 4 + r] = v;
    }
  // colsum: reduce across the 4 quads
  #pragma unroll
  for (int j = 0; j < 4; ++j) {
    float v = cs[j];
    v += __shfl_xor(v, 16, 64);
    v += __shfl_xor(v, 32, 64);
    if (quad == 0) red[256 + wr * 128 + wc * 64 + j * 16 + m16] = v;
  }
  __syncthreads();

  if (tid < 128) {
    denomP[(size_t)by * NROWS + row0 + tid] = red[tid] + red[128 + tid];
  } else if (bx != by) {
    int c = tid - 128;
    denomP[(size_t)bx * NROWS + col0 + c] = red[256 + c] + red[384 + c];
  }
}

// -------------------- denom slots -> -log; + 2*ln2*pos'; atomic into loss
__global__ __launch_bounds__(256) void reduce_kernel(
    const float* __restrict__ denomP, const float* __restrict__ posv,
    float* __restrict__ out) {
  int tid = threadIdx.x;
  int r = blockIdx.x * 256 + tid;  // 32 blocks cover 8192 rows
  float s = 0.f;
  #pragma unroll 8
  for (int b = 0; b < NCB; ++b) s += denomP[(size_t)b * NROWS + r];
  float v = -logf(s);
  // posv = 2*sim/ln2; need 4*sim (rows r and r+NHALF) = 2*ln2*posv
  if (r < NHALF) v += 1.38629436112f * posv[r];
  #pragma unroll
  for (int off = 32; off; off >>= 1) v += __shfl_down(v, off, 64);
  __shared__ float s4[4];
  if ((tid & 63) == 0) s4[tid >> 6] = v;
  __syncthreads();
  if (tid == 0)
    atomicAdd(out, (s4[0] + s4[1] + s4[2] + s4[3]) * (1.0f / 8192.0f));
}

extern "C" void kernel_launch(void* const* d_in, const int* in_sizes, int n_in,
                              void* d_out, int out_size, void* d_ws,
                              size_t ws_size, hipStream_t stream) {
  const float* emb_i = (const float*)d_in[0];
  const float* emb_j = (const float*)d_in[1];
  unsigned short* zbF = (unsigned short*)d_ws;           // 4 MB (frag layout)
  float* denomP = (float*)(zbF + (size_t)NROWS * DIM);   // 64*8192 f32 (2 MB)
  float* posv = denomP + (size_t)NCB * NROWS;            // 4096 f32
  float* out = (float*)d_out;

  normalize_kernel<<<NROWS / 16, 256, 0, stream>>>(emb_i, emb_j, zbF, out);
  denom_kernel<<<NTRI, 256, 0, stream>>>(zbF, denomP, posv);
  reduce_kernel<<<NROWS / 256, 256, 0, stream>>>(denomP, posv, out);
}